// Round 10
// baseline (239.086 us; speedup 1.0000x reference)
//
#include <hip/hip_runtime.h>

typedef __attribute__((ext_vector_type(8))) short bf16x8;
typedef __attribute__((ext_vector_type(4))) float f32x4;
typedef __attribute__((ext_vector_type(16))) float f32x16;
typedef __attribute__((ext_vector_type(4))) short short4v;

namespace {
constexpr int B = 8;
constexpr int N = 1568;
constexpr int NP = 1664;                 // padded rows: 13 q-tiles x 128
constexpr int C = 768;
constexpr int H = 12;
constexpr int D = 64;
constexpr int M = B * N;                 // 12544
constexpr int NT = 25;                   // kv tiles of 64
constexpr int QT = 13;                   // q tiles of 128
constexpr size_t QKP = (size_t)B * H * NP * D;
// ws layout (ushort): xb | Wb | q | k | vT
constexpr size_t OFF_XB = 0;
constexpr size_t OFF_WB = OFF_XB + (size_t)M * C;
constexpr size_t OFF_Q  = OFF_WB + (size_t)3 * C * C;
constexpr size_t OFF_K  = OFF_Q + QKP;
constexpr size_t OFF_VT = OFF_K + QKP;
constexpr float LOG2E = 1.44269504088896f;
}

__device__ __forceinline__ ushort f2bf(float f) {
    union { float f; unsigned u; } a; a.f = f;
    unsigned u = a.u;
    u += 0x7FFF + ((u >> 16) & 1);   // RNE
    return (ushort)(u >> 16);
}
__device__ __forceinline__ void gload16(const ushort* g, ushort* l) {
    __builtin_amdgcn_global_load_lds(
        (const __attribute__((address_space(1))) ushort*)g,
        (__attribute__((address_space(3))) ushort*)l, 16, 0, 0);
}
__device__ __forceinline__ unsigned cvtpk(float lo, float hi) {
    unsigned r;
    asm("v_cvt_pk_bf16_f32 %0, %1, %2" : "=v"(r) : "v"(lo), "v"(hi));
    return r;
}
__device__ __forceinline__ void plswap(unsigned &a, unsigned &b) {
    asm("v_permlane32_swap_b32 %0, %1" : "+v"(a), "+v"(b));
}

// ---------------------------------------------------------------------------
// Prepass: fp32 -> bf16 for x and W.
// ---------------------------------------------------------------------------
__global__ __launch_bounds__(256) void cvt_bf16_kernel(
    const float* __restrict__ x, const float* __restrict__ W,
    ushort* __restrict__ xb, ushort* __restrict__ wb)
{
    constexpr int NX = M * C / 4;
    constexpr int NW = 3 * C * C / 4;
    for (int i = blockIdx.x * blockDim.x + threadIdx.x; i < NX + NW;
         i += gridDim.x * blockDim.x) {
        float4 v; ushort* dst; int o;
        if (i < NX) { v = ((const float4*)x)[i]; dst = xb; o = i; }
        else        { v = ((const float4*)W)[i - NX]; dst = wb; o = i - NX; }
        short4v s;
        s.x = (short)f2bf(v.x); s.y = (short)f2bf(v.y);
        s.z = (short)f2bf(v.z); s.w = (short)f2bf(v.w);
        *(short4v*)(dst + (size_t)o * 4) = s;
    }
}

// ---------------------------------------------------------------------------
// Shared K-loop macro body (128x128 tile, BK=64, global_load_lds w=16 with
// pre-swizzled source). Macro so each kernel compiles ONE single-path loop
// (round-8 lesson: uniform branch around the MFMA loop breaks pipelining).
// ---------------------------------------------------------------------------
#define QKV_STAGE_AND_FRAGS()                                                 \
    for (int kb = 0; kb < C; kb += 64) {                                      \
        __syncthreads();                                                      \
        _Pragma("unroll")                                                     \
        for (int i = 0; i < 4; ++i) {                                         \
            const int R = (w * 4 + i) * 8 + Rr;                               \
            const int cgx = (cch ^ (R & 7)) * 8;                              \
            gload16(xb + (size_t)(m0 + R) * C + kb + cgx,                     \
                    &Ab[0][0] + (w * 4 + i) * 512);                           \
            gload16(Wb + (size_t)(j0 + R) * C + kb + cgx,                     \
                    &Bb[0][0] + (w * 4 + i) * 512);                           \
        }                                                                     \
        __syncthreads();                                                      \
        _Pragma("unroll")                                                     \
        for (int kk = 0; kk < 2; ++kk) {                                      \
            bf16x8 af[4], bfr[4];                                             \
            _Pragma("unroll")                                                 \
            for (int t = 0; t < 4; ++t) {                                     \
                const int ra = wr * 64 + t * 16 + l15;                        \
                af[t]  = *(const bf16x8*)&Ab[ra][((kk * 4 + lg) ^ (ra & 7)) * 8]; \
                const int rb = wc * 64 + t * 16 + l15;                        \
                bfr[t] = *(const bf16x8*)&Bb[rb][((kk * 4 + lg) ^ (rb & 7)) * 8]; \
            }                                                                 \
            MFMA_BLOCK()                                                      \
        }                                                                     \
    }

// ---------------------------------------------------------------------------
// q/k GEMM (j-tiles 0..11). Swapped operands: D[j][m] -> C/D col = m (one n
// per lane), rows = 4 consecutive j = consecutive d. Row-norm = 2 shfls;
// store = packed 8B into [bh][n pad][d].
// ---------------------------------------------------------------------------
__global__ __launch_bounds__(256) void qk_mfma_kernel(
    const ushort* __restrict__ xb, const ushort* __restrict__ Wb,
    const float* __restrict__ bias, ushort* __restrict__ qg,
    ushort* __restrict__ kg)
{
    __shared__ __align__(16) ushort Ab[128][64];
    __shared__ __align__(16) ushort Bb[128][64];

    const int tid = threadIdx.x;
    const int l = tid & 63;
    const int w = tid >> 6;
    const int l15 = l & 15, lg = l >> 4;

    // XCD swizzle: nwg = 1176 = 8 * 147 exactly
    const int orig = blockIdx.x;
    const int wgid = (orig & 7) * 147 + (orig >> 3);
    const int mt = wgid / 12;
    const int jt = wgid - mt * 12;
    const int m0 = mt * 128;
    const int j0 = jt * 128;

    const int wr = w >> 1, wc = w & 1;
    const int Rr = l >> 3;
    const int cch = l & 7;

    f32x4 acc[4][4] = {};

#define MFMA_BLOCK()                                                          \
            _Pragma("unroll")                                                 \
            for (int mi = 0; mi < 4; ++mi)                                    \
                _Pragma("unroll")                                             \
                for (int nj = 0; nj < 4; ++nj)                                \
                    acc[mi][nj] = __builtin_amdgcn_mfma_f32_16x16x32_bf16(    \
                        bfr[nj], af[mi], acc[mi][nj], 0, 0, 0);
    QKV_STAGE_AND_FRAGS()
#undef MFMA_BLOCK

    const int sel = jt / 6;                  // 0 = q, 1 = k (uniform)
    ushort* dst = (sel == 0) ? qg : kg;
    const float scl = (sel == 0) ? LOG2E : 1.f;
    const int jbase = j0 + wc * 64;          // one head's 64-col block
    const int h = (jbase - sel * C) >> 6;
    float4 b4[4];
    #pragma unroll
    for (int nj = 0; nj < 4; ++nj)
        b4[nj] = *(const float4*)&bias[jbase + nj * 16 + lg * 4];
    #pragma unroll
    for (int mi = 0; mi < 4; ++mi) {
        float vals[16];
        float ssq = 0.f;
        #pragma unroll
        for (int nj = 0; nj < 4; ++nj) {
            #pragma unroll
            for (int r = 0; r < 4; ++r) {
                const float v = acc[mi][nj][r] + ((const float*)&b4[nj])[r];
                vals[nj * 4 + r] = v;
                ssq += v * v;
            }
        }
        ssq += __shfl_xor(ssq, 16);
        ssq += __shfl_xor(ssq, 32);
        const float inv = scl / fmaxf(sqrtf(ssq), 1e-12f);
        const int m = m0 + wr * 64 + mi * 16 + l15;
        const int b_ = m / N, n_ = m - b_ * N;
        ushort* o = dst + (((size_t)b_ * H + h) * NP + n_) * D;
        #pragma unroll
        for (int nj = 0; nj < 4; ++nj) {
            short4v s;
            s.x = (short)f2bf(vals[nj * 4 + 0] * inv);
            s.y = (short)f2bf(vals[nj * 4 + 1] * inv);
            s.z = (short)f2bf(vals[nj * 4 + 2] * inv);
            s.w = (short)f2bf(vals[nj * 4 + 3] * inv);
            *(short4v*)(o + nj * 16 + lg * 4) = s;
        }
    }
}

// ---------------------------------------------------------------------------
// v GEMM (j-tiles 12..17). Normal order: rows = 4 consecutive n -> packed
// 8B transposed stores into [bh][d][n pad] (LINEAR logical layout).
// ---------------------------------------------------------------------------
__global__ __launch_bounds__(256) void v_mfma_kernel(
    const ushort* __restrict__ xb, const ushort* __restrict__ Wb,
    const float* __restrict__ bias, ushort* __restrict__ vtg)
{
    __shared__ __align__(16) ushort Ab[128][64];
    __shared__ __align__(16) ushort Bb[128][64];

    const int tid = threadIdx.x;
    const int l = tid & 63;
    const int w = tid >> 6;
    const int l15 = l & 15, lg = l >> 4;

    // bijective XCD swizzle: nwg = 588, q = 73, r = 4
    const int orig = blockIdx.x;
    const int xcd = orig & 7;
    const int base = (xcd < 4) ? xcd * 74 : 4 * 74 + (xcd - 4) * 73;
    const int wgid = base + (orig >> 3);
    const int mt = wgid / 6;
    const int jtv = wgid - mt * 6;
    const int m0 = mt * 128;
    const int j0 = (12 + jtv) * 128;

    const int wr = w >> 1, wc = w & 1;
    const int Rr = l >> 3;
    const int cch = l & 7;

    f32x4 acc[4][4] = {};

#define MFMA_BLOCK()                                                          \
            _Pragma("unroll")                                                 \
            for (int mi = 0; mi < 4; ++mi)                                    \
                _Pragma("unroll")                                             \
                for (int nj = 0; nj < 4; ++nj)                                \
                    acc[mi][nj] = __builtin_amdgcn_mfma_f32_16x16x32_bf16(    \
                        af[mi], bfr[nj], acc[mi][nj], 0, 0, 0);
    QKV_STAGE_AND_FRAGS()
#undef MFMA_BLOCK

    #pragma unroll
    for (int nj = 0; nj < 4; ++nj) {
        const int jcol = j0 + wc * 64 + nj * 16 + l15;
        const int rem = jcol - 2 * C;
        const int h = rem >> 6, d = rem & 63;
        const float bb = bias[jcol];
        #pragma unroll
        for (int mi = 0; mi < 4; ++mi) {
            const int mb = m0 + wr * 64 + mi * 16 + lg * 4;   // 4-aligned
            const int b_ = mb / N, n_ = mb - b_ * N;
            short4v o;
            o.x = (short)f2bf(acc[mi][nj][0] + bb);
            o.y = (short)f2bf(acc[mi][nj][1] + bb);
            o.z = (short)f2bf(acc[mi][nj][2] + bb);
            o.w = (short)f2bf(acc[mi][nj][3] + bb);
            *(short4v*)&vtg[(((size_t)b_ * H + h) * D + d) * NP + n_] = o;
        }
    }
}

// ---------------------------------------------------------------------------
// Cosine attention, swapped-QK^T 32x32x16 + in-register softmax (T12).
// Q fragments AND V fragments read direct from global to registers (V's PV
// B-fragment = 16B contiguous at vtg[bh][d][kt*64 + chunk] -- same pattern
// as Q). Only K is LDS-staged (double-buffered, 16 KiB total). V loads
// issue at loop-top so L2 latency hides under QK+softmax. One barrier/kt.
// ---------------------------------------------------------------------------
__global__ __launch_bounds__(256) void attn_kernel(
    const ushort* __restrict__ qg, const ushort* __restrict__ kg,
    const ushort* __restrict__ vtg, float* __restrict__ out)
{
    __shared__ __align__(16) ushort KsB[2][64 * 64];

    const int tid = threadIdx.x;
    const int l   = tid & 63;
    const int w   = tid >> 6;
    const int l31 = l & 31;
    const int hi  = l >> 5;

    const int bid = blockIdx.x;
    const int grp = bid >> 3;                 // 0..155
    const int qt  = grp % QT;
    const int bh  = (bid & 7) + 8 * (grp / QT);

    const ushort* qp  = qg  + (size_t)bh * NP * D;
    const ushort* kp  = kg  + (size_t)bh * NP * D;
    const ushort* vtp = vtg + (size_t)bh * D * NP;

    const int rsub = l >> 3;
    const int cg   = ((l & 7) ^ rsub) << 3;   // pre-swizzled source chunk (K)

    // ---- Q fragments straight from global (logical d-order) ----
    bf16x8 qf[4];
    {
        const ushort* qr = qp + (size_t)(qt * 128 + w * 32 + l31) * D + hi * 8;
        #pragma unroll
        for (int ds = 0; ds < 4; ++ds)
            qf[ds] = *(const bf16x8*)(qr + ds * 16);
    }

    // ---- prologue DMA: K tile 0 ----
    #pragma unroll
    for (int p = 0; p < 2; ++p) {
        const int rb = p * 32 + w * 8;
        gload16(kp + (size_t)(rb + rsub) * D + cg, KsB[0] + rb * 64);
    }
    __syncthreads();

    f32x16 o_acc[2] = {};
    float denom = 0.f;
    int cur = 0;

    for (int kt = 0; kt < NT; ++kt) {
        // ---- V fragments for THIS tile: direct global, issued early ----
        bf16x8 vf[2][4];
        #pragma unroll
        for (int dt = 0; dt < 2; ++dt) {
            const ushort* vr = vtp + (size_t)(dt * 32 + l31) * NP + kt * 64 + hi * 8;
            #pragma unroll
            for (int ks = 0; ks < 4; ++ks)
                vf[dt][ks] = *(const bf16x8*)(vr + ks * 16);
        }

        // ---- issue next K tile's DMA ----
        if (kt + 1 < NT) {
            ushort* Kn = KsB[cur ^ 1];
            #pragma unroll
            for (int p = 0; p < 2; ++p) {
                const int rb = p * 32 + w * 8;
                gload16(kp + (size_t)((kt + 1) * 64 + rb + rsub) * D + cg, Kn + rb * 64);
            }
        }
        const ushort* Kc = KsB[cur];

        // ---- S^T = K Q (pre-scaled by log2e), exp2, pack ----
        unsigned pw[16];
        #pragma unroll
        for (int f = 0; f < 2; ++f) {
            if (f == 1 && kt == NT - 1) {
                #pragma unroll
                for (int i = 0; i < 8; ++i) pw[8 + i] = 0;   // pad kv rows
            } else {
                f32x16 st = {};
                __builtin_amdgcn_s_setprio(1);
                #pragma unroll
                for (int ds = 0; ds < 4; ++ds) {
                    const int krow = f * 32 + l31;
                    const int ch = (2 * ds + hi) ^ (krow & 7);
                    const bf16x8 kf = *(const bf16x8*)(Kc + krow * 64 + ch * 8);
                    st = __builtin_amdgcn_mfma_f32_32x32x16_bf16(kf, qf[ds], st, 0, 0, 0);
                }
                __builtin_amdgcn_s_setprio(0);
                float p[16];
                #pragma unroll
                for (int r = 0; r < 16; ++r) p[r] = __builtin_amdgcn_exp2f(st[r]);
                const float t =
                    (((p[0]+p[1])+(p[2]+p[3])) + ((p[4]+p[5])+(p[6]+p[7]))) +
                    (((p[8]+p[9])+(p[10]+p[11])) + ((p[12]+p[13])+(p[14]+p[15])));
                denom += t;
                #pragma unroll
                for (int i = 0; i < 8; ++i)
                    pw[f * 8 + i] = cvtpk(p[2 * i], p[2 * i + 1]);
            }
        }

        // ---- redistribute: words -> PV A-fragments (T12 permlane recipe) ----
        #pragma unroll
        for (int q4 = 0; q4 < 4; ++q4) {
            plswap(pw[q4 * 4 + 0], pw[q4 * 4 + 2]);
            plswap(pw[q4 * 4 + 1], pw[q4 * 4 + 3]);
        }

        // ---- O += P V (V from registers) ----
        __builtin_amdgcn_s_setprio(1);
        #pragma unroll
        for (int dt = 0; dt < 2; ++dt) {
            #pragma unroll
            for (int ks = 0; ks < 4; ++ks) {
                union { unsigned u[4]; bf16x8 v; } A;
                A.u[0] = pw[ks * 4 + 0]; A.u[1] = pw[ks * 4 + 1];
                A.u[2] = pw[ks * 4 + 2]; A.u[3] = pw[ks * 4 + 3];
                o_acc[dt] = __builtin_amdgcn_mfma_f32_32x32x16_bf16(
                    A.v, vf[dt][ks], o_acc[dt], 0, 0, 0);
            }
        }
        __builtin_amdgcn_s_setprio(0);

        __syncthreads();   // drains next K DMA; all waves done with Kc
        cur ^= 1;
    }

    // ---- epilogue: reduce denom, broadcast via (freed) K LDS ----
    denom += __shfl_xor(denom, 32);
    float* dn = (float*)&KsB[0][0];
    if (hi == 0) dn[w * 32 + l31] = 1.f / denom;
    __syncthreads();

    const int b_ = bh / H;
    const int h_ = bh % H;
    #pragma unroll
    for (int g = 0; g < 4; ++g) {
        const f32x4 inv4 = *(const f32x4*)&dn[w * 32 + g * 8 + hi * 4];
        #pragma unroll
        for (int r3 = 0; r3 < 4; ++r3) {
            const int n = qt * 128 + w * 32 + g * 8 + hi * 4 + r3;
            if (n < N) {
                const float iv = inv4[r3];
                #pragma unroll
                for (int dt = 0; dt < 2; ++dt)
                    out[((size_t)b_ * N + n) * C + (h_ << 6) + dt * 32 + l31] =
                        o_acc[dt][g * 4 + r3] * iv;
            }
        }
    }
}

extern "C" void kernel_launch(void* const* d_in, const int* in_sizes, int n_in,
                              void* d_out, int out_size, void* d_ws, size_t ws_size,
                              hipStream_t stream) {
    const float* x  = (const float*)d_in[0];
    const float* Wq = (const float*)d_in[1];
    const float* bq = (const float*)d_in[2];
    float* out = (float*)d_out;
    ushort* ws = (ushort*)d_ws;

    ushort* xb  = ws + OFF_XB;
    ushort* wb  = ws + OFF_WB;
    ushort* qg  = ws + OFF_Q;
    ushort* kg  = ws + OFF_K;
    ushort* vtg = ws + OFF_VT;

    cvt_bf16_kernel<<<2048, 256, 0, stream>>>(x, Wq, xb, wb);
    qk_mfma_kernel<<<98 * 12, 256, 0, stream>>>(xb, wb, bq, qg, kg);
    v_mfma_kernel<<<98 * 6, 256, 0, stream>>>(xb, wb, bq, vtg);
    attn_kernel<<<QT * B * H, 256, 0, stream>>>(qg, kg, vtg, out);
}

// Round 11
// 173.423 us; speedup vs baseline: 1.3786x; 1.3786x over previous
//
#include <hip/hip_runtime.h>

typedef __attribute__((ext_vector_type(8))) short bf16x8;
typedef __attribute__((ext_vector_type(4))) float f32x4;
typedef __attribute__((ext_vector_type(16))) float f32x16;
typedef __attribute__((ext_vector_type(4))) short short4v;

namespace {
constexpr int B = 8;
constexpr int N = 1568;
constexpr int NP = 1664;                 // padded rows: 13 q-tiles x 128
constexpr int C = 768;
constexpr int H = 12;
constexpr int D = 64;
constexpr int M = B * N;                 // 12544
constexpr int NT = 25;                   // kv tiles of 64
constexpr int QT = 13;                   // q tiles of 128
constexpr size_t QKP = (size_t)B * H * NP * D;
// ws layout (ushort): xb | Wb | q | k | vT
constexpr size_t OFF_XB = 0;
constexpr size_t OFF_WB = OFF_XB + (size_t)M * C;
constexpr size_t OFF_Q  = OFF_WB + (size_t)3 * C * C;
constexpr size_t OFF_K  = OFF_Q + QKP;
constexpr size_t OFF_VT = OFF_K + QKP;
constexpr float LOG2E = 1.44269504088896f;
}

__device__ __forceinline__ ushort f2bf(float f) {
    union { float f; unsigned u; } a; a.f = f;
    unsigned u = a.u;
    u += 0x7FFF + ((u >> 16) & 1);   // RNE
    return (ushort)(u >> 16);
}
__device__ __forceinline__ void gload16(const ushort* g, ushort* l) {
    __builtin_amdgcn_global_load_lds(
        (const __attribute__((address_space(1))) ushort*)g,
        (__attribute__((address_space(3))) ushort*)l, 16, 0, 0);
}
__device__ __forceinline__ unsigned cvtpk(float lo, float hi) {
    unsigned r;
    asm("v_cvt_pk_bf16_f32 %0, %1, %2" : "=v"(r) : "v"(lo), "v"(hi));
    return r;
}
__device__ __forceinline__ void plswap(unsigned &a, unsigned &b) {
    asm("v_permlane32_swap_b32 %0, %1" : "+v"(a), "+v"(b));
}

// ---------------------------------------------------------------------------
// Prepass: fp32 -> bf16 for x and W.
// ---------------------------------------------------------------------------
__global__ __launch_bounds__(256) void cvt_bf16_kernel(
    const float* __restrict__ x, const float* __restrict__ W,
    ushort* __restrict__ xb, ushort* __restrict__ wb)
{
    constexpr int NX = M * C / 4;
    constexpr int NW = 3 * C * C / 4;
    for (int i = blockIdx.x * blockDim.x + threadIdx.x; i < NX + NW;
         i += gridDim.x * blockDim.x) {
        float4 v; ushort* dst; int o;
        if (i < NX) { v = ((const float4*)x)[i]; dst = xb; o = i; }
        else        { v = ((const float4*)W)[i - NX]; dst = wb; o = i - NX; }
        short4v s;
        s.x = (short)f2bf(v.x); s.y = (short)f2bf(v.y);
        s.z = (short)f2bf(v.z); s.w = (short)f2bf(v.w);
        *(short4v*)(dst + (size_t)o * 4) = s;
    }
}

// ---------------------------------------------------------------------------
// QKV GEMM (round-7 config restored): bf16 MFMA 128x128 BK=64, single-path
// main loop. Epilogue: q rows scaled by LOG2E/||q||, k rows by 1/||k||,
// scalar 2B scatter to [bh][n pad1664][d]; v -> [bh][d][n pad1664] packed
// 8B transposed stores.
// ---------------------------------------------------------------------------
__global__ __launch_bounds__(256) void qkv_mfma_kernel(
    const ushort* __restrict__ xb, const ushort* __restrict__ Wb,
    const float* __restrict__ bias, ushort* __restrict__ qg,
    ushort* __restrict__ kg, ushort* __restrict__ vtg)
{
    __shared__ __align__(16) ushort Ab[128][64];
    __shared__ __align__(16) ushort Bb[128][64];

    const int tid = threadIdx.x;
    const int l = tid & 63;
    const int w = tid >> 6;
    const int l15 = l & 15, lg = l >> 4;

    // bijective XCD swizzle (nwg=1764, q=220, r=4)
    const int orig = blockIdx.x;
    const int xcd = orig & 7;
    const int base = (xcd < 4) ? xcd * 221 : 4 * 221 + (xcd - 4) * 220;
    const int wgid = base + (orig >> 3);
    const int mt = wgid / 18;
    const int jt = wgid - mt * 18;
    const int m0 = mt * 128;
    const int j0 = jt * 128;

    const int wr = w >> 1, wc = w & 1;
    const int Rr = l >> 3;
    const int cch = l & 7;

    f32x4 acc[4][4] = {};

    for (int kb = 0; kb < C; kb += 64) {
        __syncthreads();
        #pragma unroll
        for (int i = 0; i < 4; ++i) {
            const int R = (w * 4 + i) * 8 + Rr;
            const int cg = (cch ^ (R & 7)) * 8;
            gload16(xb + (size_t)(m0 + R) * C + kb + cg, &Ab[0][0] + (w * 4 + i) * 512);
            gload16(Wb + (size_t)(j0 + R) * C + kb + cg, &Bb[0][0] + (w * 4 + i) * 512);
        }
        __syncthreads();

        #pragma unroll
        for (int kk = 0; kk < 2; ++kk) {
            bf16x8 af[4], bfr[4];
            #pragma unroll
            for (int t = 0; t < 4; ++t) {
                const int ra = wr * 64 + t * 16 + l15;
                af[t]  = *(const bf16x8*)&Ab[ra][((kk * 4 + lg) ^ (ra & 7)) * 8];
                const int rb = wc * 64 + t * 16 + l15;
                bfr[t] = *(const bf16x8*)&Bb[rb][((kk * 4 + lg) ^ (rb & 7)) * 8];
            }
            #pragma unroll
            for (int mi = 0; mi < 4; ++mi)
                #pragma unroll
                for (int nj = 0; nj < 4; ++nj)
                    acc[mi][nj] = __builtin_amdgcn_mfma_f32_16x16x32_bf16(
                        af[mi], bfr[nj], acc[mi][nj], 0, 0, 0);
        }
    }

    const int sel = jt / 6;
    if (sel < 2) {
        ushort* dst = (sel == 0) ? qg : kg;
        const float scl = (sel == 0) ? LOG2E : 1.f;
        const int jbase = j0 + wc * 64;
        const int h = (jbase - sel * C) >> 6;
        float bbv[4];
        #pragma unroll
        for (int nj = 0; nj < 4; ++nj) bbv[nj] = bias[jbase + nj * 16 + l15];
        #pragma unroll
        for (int mi = 0; mi < 4; ++mi) {
            #pragma unroll
            for (int r = 0; r < 4; ++r) {
                const float v0 = acc[mi][0][r] + bbv[0];
                const float v1 = acc[mi][1][r] + bbv[1];
                const float v2 = acc[mi][2][r] + bbv[2];
                const float v3 = acc[mi][3][r] + bbv[3];
                float ssq = v0*v0 + v1*v1 + v2*v2 + v3*v3;
                ssq += __shfl_xor(ssq, 1); ssq += __shfl_xor(ssq, 2);
                ssq += __shfl_xor(ssq, 4); ssq += __shfl_xor(ssq, 8);
                const float inv = scl / fmaxf(sqrtf(ssq), 1e-12f);
                const int m = m0 + wr * 64 + mi * 16 + lg * 4 + r;
                const int b_ = m / N, n_ = m - b_ * N;
                ushort* o = dst + (((size_t)b_ * H + h) * NP + n_) * D + l15;
                o[0]  = f2bf(v0 * inv);
                o[16] = f2bf(v1 * inv);
                o[32] = f2bf(v2 * inv);
                o[48] = f2bf(v3 * inv);
            }
        }
    } else {
        #pragma unroll
        for (int nj = 0; nj < 4; ++nj) {
            const int jcol = j0 + wc * 64 + nj * 16 + l15;
            const int rem = jcol - 2 * C;
            const int h = rem >> 6, d = rem & 63;
            const float bb = bias[jcol];
            #pragma unroll
            for (int mi = 0; mi < 4; ++mi) {
                const int mb = m0 + wr * 64 + mi * 16 + lg * 4;
                const int b_ = mb / N, n_ = mb - b_ * N;
                short4v o;
                o.x = (short)f2bf(acc[mi][nj][0] + bb);
                o.y = (short)f2bf(acc[mi][nj][1] + bb);
                o.z = (short)f2bf(acc[mi][nj][2] + bb);
                o.w = (short)f2bf(acc[mi][nj][3] + bb);
                *(short4v*)&vtg[(((size_t)b_ * H + h) * D + d) * NP + n_] = o;
            }
        }
    }
}

// ---------------------------------------------------------------------------
// Cosine attention, swapped-QK^T 32x32x16 + in-register softmax (T12).
// K/V double-buffered in LDS (32 KiB). T14 async-STAGE: next tile's K/V
// loaded global->REGISTERS at loop top (latency hides under full compute),
// ds_write'd to the spare buffer just before the barrier -> the barrier no
// longer drains an in-flight LDS-DMA. Same LDS image as the gload_lds path
// (pre-swizzled source, linear base+lane*16 dest).
// ---------------------------------------------------------------------------
__global__ __launch_bounds__(256) void attn_kernel(
    const ushort* __restrict__ qg, const ushort* __restrict__ kg,
    const ushort* __restrict__ vtg, float* __restrict__ out)
{
    __shared__ __align__(16) ushort KsB[2][64 * 64];
    __shared__ __align__(16) ushort VtB[2][64 * 64];

    const int tid = threadIdx.x;
    const int l   = tid & 63;
    const int w   = tid >> 6;
    const int l31 = l & 31;
    const int hi  = l >> 5;

    const int bid = blockIdx.x;
    const int grp = bid >> 3;                 // 0..155
    const int qt  = grp % QT;
    const int bh  = (bid & 7) + 8 * (grp / QT);

    const ushort* qp  = qg  + (size_t)bh * NP * D;
    const ushort* kp  = kg  + (size_t)bh * NP * D;
    const ushort* vtp = vtg + (size_t)bh * D * NP;

    const int rsub = l >> 3;
    const int cg   = ((l & 7) ^ rsub) << 3;   // pre-swizzled source chunk

    // ---- Q fragments straight from global (logical d-order) ----
    bf16x8 qf[4];
    {
        const ushort* qr = qp + (size_t)(qt * 128 + w * 32 + l31) * D + hi * 8;
        #pragma unroll
        for (int ds = 0; ds < 4; ++ds)
            qf[ds] = *(const bf16x8*)(qr + ds * 16);
    }

    // ---- prologue DMA: K/V tile 0 (gload_lds; drained by the barrier) ----
    #pragma unroll
    for (int p = 0; p < 2; ++p) {
        const int rb = p * 32 + w * 8;
        gload16(kp + (size_t)(rb + rsub) * D + cg, KsB[0] + rb * 64);
        gload16(vtp + (size_t)(rb + rsub) * NP + cg, VtB[0] + rb * 64);
    }
    __syncthreads();

    f32x16 o_acc[2] = {};
    float denom = 0.f;
    int cur = 0;

    for (int kt = 0; kt < NT; ++kt) {
        // ---- T14 issue-early: next tile's K/V into registers ----
        bf16x8 kst[2], vst[2];
        const bool hasNext = (kt + 1 < NT);
        if (hasNext) {
            #pragma unroll
            for (int p = 0; p < 2; ++p) {
                const int row = p * 32 + w * 8 + rsub;
                kst[p] = *(const bf16x8*)(kp + (size_t)((kt + 1) * 64 + row) * D + cg);
                vst[p] = *(const bf16x8*)(vtp + (size_t)row * NP + (kt + 1) * 64 + cg);
            }
        }
        const ushort* Kc = KsB[cur];
        const ushort* Vc = VtB[cur];

        // ---- S^T = K Q (pre-scaled by log2e), exp2, pack ----
        unsigned pw[16];
        #pragma unroll
        for (int f = 0; f < 2; ++f) {
            if (f == 1 && kt == NT - 1) {
                #pragma unroll
                for (int i = 0; i < 8; ++i) pw[8 + i] = 0;   // pad kv rows
            } else {
                f32x16 st = {};
                __builtin_amdgcn_s_setprio(1);
                #pragma unroll
                for (int ds = 0; ds < 4; ++ds) {
                    const int krow = f * 32 + l31;
                    const int ch = (2 * ds + hi) ^ (krow & 7);
                    const bf16x8 kf = *(const bf16x8*)(Kc + krow * 64 + ch * 8);
                    st = __builtin_amdgcn_mfma_f32_32x32x16_bf16(kf, qf[ds], st, 0, 0, 0);
                }
                __builtin_amdgcn_s_setprio(0);
                float p[16];
                #pragma unroll
                for (int r = 0; r < 16; ++r) p[r] = __builtin_amdgcn_exp2f(st[r]);
                const float t =
                    (((p[0]+p[1])+(p[2]+p[3])) + ((p[4]+p[5])+(p[6]+p[7]))) +
                    (((p[8]+p[9])+(p[10]+p[11])) + ((p[12]+p[13])+(p[14]+p[15])));
                denom += t;
                #pragma unroll
                for (int i = 0; i < 8; ++i)
                    pw[f * 8 + i] = cvtpk(p[2 * i], p[2 * i + 1]);
            }
        }

        // ---- redistribute: words -> PV A-fragments (T12 permlane recipe) ----
        #pragma unroll
        for (int q4 = 0; q4 < 4; ++q4) {
            plswap(pw[q4 * 4 + 0], pw[q4 * 4 + 2]);
            plswap(pw[q4 * 4 + 1], pw[q4 * 4 + 3]);
        }

        // ---- O += P V ----
        __builtin_amdgcn_s_setprio(1);
        #pragma unroll
        for (int dt = 0; dt < 2; ++dt) {
            #pragma unroll
            for (int ks = 0; ks < 4; ++ks) {
                const int vrow = dt * 32 + l31;
                const int ch = (2 * ks + hi) ^ (vrow & 7);
                const bf16x8 vf = *(const bf16x8*)(Vc + vrow * 64 + ch * 8);
                union { unsigned u[4]; bf16x8 v; } A;
                A.u[0] = pw[ks * 4 + 0]; A.u[1] = pw[ks * 4 + 1];
                A.u[2] = pw[ks * 4 + 2]; A.u[3] = pw[ks * 4 + 3];
                o_acc[dt] = __builtin_amdgcn_mfma_f32_32x32x16_bf16(
                    A.v, vf, o_acc[dt], 0, 0, 0);
            }
        }
        __builtin_amdgcn_s_setprio(0);

        // ---- T14 write-late: commit staged K/V to the spare buffer ----
        if (hasNext) {
            ushort* Kn = KsB[cur ^ 1];
            ushort* Vn = VtB[cur ^ 1];
            #pragma unroll
            for (int p = 0; p < 2; ++p) {
                const int rb = p * 32 + w * 8;
                *(bf16x8*)(Kn + rb * 64 + l * 8) = kst[p];
                *(bf16x8*)(Vn + rb * 64 + l * 8) = vst[p];
            }
        }
        __syncthreads();   // orders LDS writes only (no DMA in flight)
        cur ^= 1;
    }

    // ---- epilogue: reduce denom, broadcast via (freed) K LDS ----
    denom += __shfl_xor(denom, 32);
    float* dn = (float*)&KsB[0][0];
    if (hi == 0) dn[w * 32 + l31] = 1.f / denom;
    __syncthreads();

    const int b_ = bh / H;
    const int h_ = bh % H;
    #pragma unroll
    for (int g = 0; g < 4; ++g) {
        const f32x4 inv4 = *(const f32x4*)&dn[w * 32 + g * 8 + hi * 4];
        #pragma unroll
        for (int r3 = 0; r3 < 4; ++r3) {
            const int n = qt * 128 + w * 32 + g * 8 + hi * 4 + r3;
            if (n < N) {
                const float iv = inv4[r3];
                #pragma unroll
                for (int dt = 0; dt < 2; ++dt)
                    out[((size_t)b_ * N + n) * C + (h_ << 6) + dt * 32 + l31] =
                        o_acc[dt][g * 4 + r3] * iv;
            }
        }
    }
}

extern "C" void kernel_launch(void* const* d_in, const int* in_sizes, int n_in,
                              void* d_out, int out_size, void* d_ws, size_t ws_size,
                              hipStream_t stream) {
    const float* x  = (const float*)d_in[0];
    const float* Wq = (const float*)d_in[1];
    const float* bq = (const float*)d_in[2];
    float* out = (float*)d_out;
    ushort* ws = (ushort*)d_ws;

    ushort* xb  = ws + OFF_XB;
    ushort* wb  = ws + OFF_WB;
    ushort* qg  = ws + OFF_Q;
    ushort* kg  = ws + OFF_K;
    ushort* vtg = ws + OFF_VT;

    cvt_bf16_kernel<<<2048, 256, 0, stream>>>(x, Wq, xb, wb);
    qkv_mfma_kernel<<<(M / 128) * (3 * C / 128), 256, 0, stream>>>(xb, wb, bq, qg, kg, vtg);
    attn_kernel<<<QT * B * H, 256, 0, stream>>>(qg, kg, vtg, out);
}